// Round 5
// baseline (273.578 us; speedup 1.0000x reference)
//
#include <hip/hip_runtime.h>

// out[i][d] = params[idx[i]] * xs[i][d];  N=4194304, D=8, V=1048576
//
// Model (5 experiments): chip serves ~100G 64B-line transactions/s (~6.4TB/s
// line motion). Streams need 4.25M lines; 4M random 4B gathers cost 4M full
// lines (16x amplification) -> ~85us. If params stayed L2-resident, gather
// fills drop to 0.5M (each XCD reuses each of its 64K table lines ~7.6x).
//
// Decisive experiment: sc1 (device scope) on xs/idx loads = true L2
// no-allocate (hints failed in r2); nt stores = evict-first with normal
// WRITE granularity (r2-proven; r3's nt|sc1 write-through was the bug).
// params gathers keep plain policy -> only L2-allocating read -> resident.

typedef float f32x4 __attribute__((ext_vector_type(4)));
typedef int   i32x4 __attribute__((ext_vector_type(4)));

__device__ f32x4 buf_load_x4(i32x4 rsrc, int voffset, int soffset, int cpol)
    __asm("llvm.amdgcn.raw.buffer.load.v4f32");
__device__ int   buf_load_i32(i32x4 rsrc, int voffset, int soffset, int cpol)
    __asm("llvm.amdgcn.raw.buffer.load.i32");

#define CPOL_SC1 16   // sc1: device scope -> no L2 allocation on gfx950
                      // (sc0=1, nt=2, dlc=4, sc1=16)

__device__ __forceinline__ i32x4 make_rsrc(const void* p, unsigned bytes) {
    unsigned long long a = (unsigned long long)p;
    i32x4 r;
    r.x = (int)(a & 0xFFFFFFFFull);
    r.y = (int)(a >> 32);        // stride = 0
    r.z = (int)bytes;            // num_records (bytes). OOB load -> 0
    r.w = 0x00020000;            // raw untyped dword access
    return r;
}

__global__ __launch_bounds__(256) void spvar_kernel(
    const float* __restrict__ xs,
    const int*   __restrict__ idx,
    const float* __restrict__ params,
    float*       __restrict__ out,
    int nrows, int stride)   // stride = gridDim.x * blockDim.x
{
    const i32x4 rx = make_rsrc(xs,  (unsigned)nrows * 32u);
    const i32x4 ri = make_rsrc(idx, (unsigned)nrows * 4u);

    const int t = blockIdx.x * blockDim.x + threadIdx.x;
    const int r0 = t;
    const int r1 = t + stride;
    const int r2 = t + 2 * stride;
    const int r3 = t + 3 * stride;

    // idx loads: sc1 -> no L2 pollution. OOB lanes read 0 (harmless).
    const int i0 = buf_load_i32(ri, r0 * 4, 0, CPOL_SC1);
    const int i1 = buf_load_i32(ri, r1 * 4, 0, CPOL_SC1);
    const int i2 = buf_load_i32(ri, r2 * 4, 0, CPOL_SC1);
    const int i3 = buf_load_i32(ri, r3 * 4, 0, CPOL_SC1);

    // xs loads: sc1 -> no L2 pollution
    f32x4 a0 = buf_load_x4(rx, r0 * 32,      0, CPOL_SC1);
    f32x4 b0 = buf_load_x4(rx, r0 * 32 + 16, 0, CPOL_SC1);
    f32x4 a1 = buf_load_x4(rx, r1 * 32,      0, CPOL_SC1);
    f32x4 b1 = buf_load_x4(rx, r1 * 32 + 16, 0, CPOL_SC1);
    f32x4 a2 = buf_load_x4(rx, r2 * 32,      0, CPOL_SC1);
    f32x4 b2 = buf_load_x4(rx, r2 * 32 + 16, 0, CPOL_SC1);
    f32x4 a3 = buf_load_x4(rx, r3 * 32,      0, CPOL_SC1);
    f32x4 b3 = buf_load_x4(rx, r3 * 32 + 16, 0, CPOL_SC1);

    // param gathers: PLAIN policy -> the only L2-allocating reads.
    const float p0 = params[i0];
    const float p1 = params[i1];
    const float p2 = params[i2];
    const float p3 = params[i3];

    a0 *= p0; b0 *= p0;
    a1 *= p1; b1 *= p1;
    a2 *= p2; b2 *= p2;
    a3 *= p3; b3 *= p3;

    f32x4* o = (f32x4*)out;
    if (r3 < nrows) {
        __builtin_nontemporal_store(a0, o + 2 * r0);
        __builtin_nontemporal_store(b0, o + 2 * r0 + 1);
        __builtin_nontemporal_store(a1, o + 2 * r1);
        __builtin_nontemporal_store(b1, o + 2 * r1 + 1);
        __builtin_nontemporal_store(a2, o + 2 * r2);
        __builtin_nontemporal_store(b2, o + 2 * r2 + 1);
        __builtin_nontemporal_store(a3, o + 2 * r3);
        __builtin_nontemporal_store(b3, o + 2 * r3 + 1);
    } else {
        if (r0 < nrows) { __builtin_nontemporal_store(a0, o + 2*r0); __builtin_nontemporal_store(b0, o + 2*r0 + 1); }
        if (r1 < nrows) { __builtin_nontemporal_store(a1, o + 2*r1); __builtin_nontemporal_store(b1, o + 2*r1 + 1); }
        if (r2 < nrows) { __builtin_nontemporal_store(a2, o + 2*r2); __builtin_nontemporal_store(b2, o + 2*r2 + 1); }
        // r3 >= nrows here
    }
}

extern "C" void kernel_launch(void* const* d_in, const int* in_sizes, int n_in,
                              void* d_out, int out_size, void* d_ws, size_t ws_size,
                              hipStream_t stream) {
    const float* xs     = (const float*)d_in[0];   // [N, 8] f32
    const int*   idx    = (const int*)d_in[1];     // [N] int32 (jax x64 off)
    const float* params = (const float*)d_in[2];   // [V, 1] f32

    const int nrows = out_size / 8;                // N (out_size is f32 ELEMENTS, D=8)
    const int block = 256;
    const int rows_per_thread = 4;
    const int grid = (nrows + block * rows_per_thread - 1) / (block * rows_per_thread);
    const int stride = grid * block;

    spvar_kernel<<<grid, block, 0, stream>>>(
        xs, idx, params, (float*)d_out, nrows, stride);
}

// Round 6
// 260.350 us; speedup vs baseline: 1.0508x; 1.0508x over previous
//
#include <hip/hip_runtime.h>

// out[i][d] = params[idx[i]] * xs[i][d];  N=4194304, D=8, V=1048576
//
// Final model (6 experiments): the op is bound by L2<->fabric line motion
// at ~6.4-6.7 TB/s. Irreducible motion = 272 MB streams (xs+idx+out) +
// 256 MB gather line-fills (4M random 4B gathers x 64B line; params table
// cannot stay L2-resident: ~8.4 MB of interfering allocations between
// reuses vs 4 MB L2, and policy bits don't help - nt neutral, sc1 bypasses
// L3 and regressed, nt|sc1 stores doubled write traffic).
// Floor = 528 MB / 6.5 TB/s ~ 80 us/dispatch. This kernel: ~85 us.
//
// Structure: 4 rows/thread strided (idx loaded once per row, 4 independent
// gather chains), plain cache policy everywhere (best measured variant).

typedef float f32x4 __attribute__((ext_vector_type(4)));

__global__ __launch_bounds__(256) void spvar_kernel(
    const f32x4* __restrict__ xs4,
    const int*   __restrict__ idx,
    const float* __restrict__ params,
    f32x4*       __restrict__ out4,
    int nrows, int stride)   // stride = gridDim.x * blockDim.x
{
    const int t = blockIdx.x * blockDim.x + threadIdx.x;
    const int r0 = t;
    const int r1 = t + stride;
    const int r2 = t + 2 * stride;
    const int r3 = t + 3 * stride;

    if (r3 < nrows) {
        // fast path: 4 independent gather chains, all loads batched
        const int i0 = idx[r0];
        const int i1 = idx[r1];
        const int i2 = idx[r2];
        const int i3 = idx[r3];

        const float p0 = params[i0];
        const float p1 = params[i1];
        const float p2 = params[i2];
        const float p3 = params[i3];

        f32x4 a0 = xs4[2 * r0], b0 = xs4[2 * r0 + 1];
        f32x4 a1 = xs4[2 * r1], b1 = xs4[2 * r1 + 1];
        f32x4 a2 = xs4[2 * r2], b2 = xs4[2 * r2 + 1];
        f32x4 a3 = xs4[2 * r3], b3 = xs4[2 * r3 + 1];

        a0 *= p0; b0 *= p0;
        a1 *= p1; b1 *= p1;
        a2 *= p2; b2 *= p2;
        a3 *= p3; b3 *= p3;

        out4[2 * r0] = a0; out4[2 * r0 + 1] = b0;
        out4[2 * r1] = a1; out4[2 * r1 + 1] = b1;
        out4[2 * r2] = a2; out4[2 * r2 + 1] = b2;
        out4[2 * r3] = a3; out4[2 * r3 + 1] = b3;
    } else {
        // tail: per-row bounds check (last partial chunk only)
        #pragma unroll
        for (int u = 0; u < 4; ++u) {
            const int r = t + u * stride;
            if (r < nrows) {
                const float p = params[idx[r]];
                f32x4 a = xs4[2 * r];
                f32x4 b = xs4[2 * r + 1];
                a *= p; b *= p;
                out4[2 * r]     = a;
                out4[2 * r + 1] = b;
            }
        }
    }
}

extern "C" void kernel_launch(void* const* d_in, const int* in_sizes, int n_in,
                              void* d_out, int out_size, void* d_ws, size_t ws_size,
                              hipStream_t stream) {
    const float* xs     = (const float*)d_in[0];   // [N, 8] f32
    const int*   idx    = (const int*)d_in[1];     // [N] int32 (jax x64 off)
    const float* params = (const float*)d_in[2];   // [V, 1] f32

    const int nrows = out_size / 8;                // N (out_size is f32 ELEMENTS, D=8)
    const int block = 256;
    const int rows_per_thread = 4;
    const int grid = (nrows + block * rows_per_thread - 1) / (block * rows_per_thread);
    const int stride = grid * block;

    spvar_kernel<<<grid, block, 0, stream>>>(
        (const f32x4*)xs, idx, params, (f32x4*)d_out, nrows, stride);
}